// Round 9
// baseline (382.960 us; speedup 1.0000x reference)
//
#include <hip/hip_runtime.h>
#include <hip/hip_fp16.h>

#define N_NODES 50000
#define N_EDGES 800000
#define D_FEAT 64
#define K_HOPS 8
#define OUT_STRIDE ((K_HOPS + 1) * D_FEAT)  // 576
#define NPART 128                 // edge-chunk partitions (1 block/CU @ 100KB LDS)
#define CHUNK (N_EDGES / NPART)   // 6250
#define NWORD (N_NODES / 2)       // 2 nodes per u32 histogram word

#define SCAN_WORDS 512            // words per scan block = 1024 nodes
#define SCAN_NB ((NWORD + SCAN_WORDS - 1) / SCAN_WORDS)  // 49

#define NOCT (N_NODES / 8)        // 6250 octets per hop pass
#define HALF_U2 ((size_t)(N_NODES + 1) * 8)  // uint2 per y half-table (64B rows)

// ---------------- ws layout (bytes) ----------------
// No global atomics anywhere; every buffer fully overwritten -> no memset.
// P word layout per node-pair w (nodes 2w, 2w+1): byte0=src(2w), byte1=src(2w+1),
// byte2=dst(2w), byte3=dst(2w+1). Per-chunk per-node counts << 255.
// y buffers = TWO contiguous half-tables of 64B rows (features [0,32) | [32,64)):
// each half is 3.2MB < 4MB per-XCD L2 -> hop gathers are L2-resident (r8 theory:
// full 6.4MB table missed L2; hops were L2-miss-concurrency-bound at ~30us).
#define ALIGN256(x) (((x) + 255) & ~(size_t)255)
static const size_t OFF_P     = 0;                                           // u32[128][25000]
static const size_t OFF_BASES = OFF_P + (size_t)NPART * NWORD * 4;           // int[128][N]
static const size_t OFF_OFF   = ALIGN256(OFF_BASES + (size_t)NPART * N_NODES * 4); // int[N+1]
static const size_t OFF_BSUM  = ALIGN256(OFF_OFF   + (size_t)(N_NODES + 1) * 4);   // int[64]
static const size_t OFF_TOTW  = ALIGN256(OFF_BSUM  + 64 * 4);                // u32[NWORD]
static const size_t OFF_DINV  = ALIGN256(OFF_TOTW  + (size_t)NWORD * 4);     // float[N]
static const size_t OFF_CSR   = ALIGN256(OFF_DINV  + (size_t)N_NODES * 4);   // int[E]
static const size_t OFF_XA    = ALIGN256(OFF_CSR   + (size_t)N_EDGES * 4);   // 2 halves
static const size_t OFF_XB    = ALIGN256(OFF_XA + (size_t)2 * HALF_U2 * 8);

__device__ __forceinline__ unsigned pack_h2(float a, float b) {
    union { __half2 h; unsigned u; } c;
    c.h = __floats2half2_rn(a, b);
    return c.u;
}
__device__ __forceinline__ float2 unpack_h2(unsigned u) {
    union { unsigned u; __half2 h; } c;
    c.u = u;
    return __half22float2(c.h);
}

// ---------------- preprocessing: zero-global-atomic counting sort ----------------

// ONE pass: per-chunk LDS histogram of src AND dst packed 4xu8 per word.
__global__ __launch_bounds__(256, 1) void k_hist(const int* __restrict__ src,
                                                 const int* __restrict__ dst,
                                                 unsigned* __restrict__ p) {
    __shared__ unsigned h[NWORD];  // 100,000 B
    int t = threadIdx.x;
    int base = blockIdx.x * CHUNK;
    for (int w = t; w < NWORD; w += 256) h[w] = 0u;
    __syncthreads();
    for (int j = t; j < CHUNK; j += 256) {
        int s = src[base + j], d = dst[base + j];
        if (s != d) {
            atomicAdd(&h[s >> 1], 1u << (8 * (s & 1)));        // src: bytes 0/1
            atomicAdd(&h[d >> 1], 65536u << (8 * (d & 1)));    // dst: bytes 2/3
        }
    }
    __syncthreads();
    unsigned* o = p + (size_t)blockIdx.x * NWORD;
    for (int w = t; w < NWORD; w += 256) o[w] = h[w];
}

// One coalesced reduction of the packed partials -> dinv (from src bytes)
// AND totW (dst totals, u16-packed). Byte-lane sums stay < 256 (deg <= ~60).
__global__ void k_sum(const unsigned* __restrict__ p, float* __restrict__ dinv,
                      unsigned* __restrict__ totW) {
    int w = blockIdx.x * blockDim.x + threadIdx.x;
    if (w >= NWORD) return;
    unsigned s0 = 0, s1 = 0, s2 = 0, s3 = 0;
    #pragma unroll 4
    for (int c = 0; c < NPART; c += 4) {
        s0 += p[(size_t)(c + 0) * NWORD + w];
        s1 += p[(size_t)(c + 1) * NWORD + w];
        s2 += p[(size_t)(c + 2) * NWORD + w];
        s3 += p[(size_t)(c + 3) * NWORD + w];
    }
    unsigned s = (s0 + s1) + (s2 + s3);
    dinv[2 * w + 0] = rsqrtf((float)((s & 0xffu) + 1u));          // +1 self loop
    dinv[2 * w + 1] = rsqrtf((float)(((s >> 8) & 0xffu) + 1u));
    totW[w] = ((s >> 16) & 0xffu) | ((s >> 24) << 16);            // dst degs packed u16
}

// scan stage 1: per-block (1024 nodes) sums of totW (100KB total)
__global__ void k_scan_sums(const unsigned* __restrict__ totW, int* __restrict__ bsum) {
    __shared__ int lds[256];
    int b = blockIdx.x, t = threadIdx.x;
    int wend = min((b + 1) * SCAN_WORDS, NWORD);
    int tot = 0;
    for (int w = b * SCAN_WORDS + t; w < wend; w += 256) {
        unsigned v = totW[w];
        tot += (int)(v & 0xffffu) + (int)(v >> 16);
    }
    lds[t] = tot; __syncthreads();
    for (int str = 128; str > 0; str >>= 1) {
        if (t < str) lds[t] += lds[t + str];
        __syncthreads();
    }
    if (t == 0) bsum[b] = lds[0];
}

// scan stage 2: single-wave exclusive scan of the 49 block sums
__global__ void k_scan_top(int* __restrict__ bsum) {
    int lane = threadIdx.x;  // blockDim = 64
    int orig = (lane < SCAN_NB) ? bsum[lane] : 0;
    int v = orig;
    for (int d = 1; d < 64; d <<= 1) {
        int u = __shfl_up(v, d, 64);
        if (lane >= d) v += u;
    }
    if (lane < SCAN_NB) bsum[lane] = v - orig;  // exclusive
}

// scan stage 3: down-sweep writing off[] only
__global__ void k_scan_downA(const unsigned* __restrict__ totW, const int* __restrict__ bsum,
                             int* __restrict__ off) {
    __shared__ int lds[256];
    int b = blockIdx.x, t = threadIdx.x;
    int w0 = b * SCAN_WORDS + 2 * t;
    unsigned t0 = (w0 < NWORD) ? totW[w0] : 0u;
    unsigned t1 = (w0 + 1 < NWORD) ? totW[w0 + 1] : 0u;
    int n[4] = { (int)(t0 & 0xffffu), (int)(t0 >> 16),
                 (int)(t1 & 0xffffu), (int)(t1 >> 16) };
    int tsum = (n[0] + n[1]) + (n[2] + n[3]);
    lds[t] = tsum; __syncthreads();
    int x = tsum;
    for (int d = 1; d < 256; d <<= 1) {   // Hillis-Steele inclusive scan
        int u = (t >= d) ? lds[t - d] : 0;
        __syncthreads();
        x += u;
        lds[t] = x;
        __syncthreads();
    }
    int pfx = (x - tsum) + bsum[b];
    #pragma unroll
    for (int j = 0; j < 4; ++j) {
        int node = 2 * w0 + j;
        if (node < N_NODES) {
            off[node] = pfx;
            pfx += n[j];
        } else if (node == N_NODES) {
            off[node] = pfx;
        }
    }
}

// bases[c][node] = off[node] + prefix over chunks of per-chunk dst count.
__global__ void k_bases(const unsigned* __restrict__ p, const int* __restrict__ off,
                        int* __restrict__ bases) {
    int node = blockIdx.x * blockDim.x + threadIdx.x;
    if (node >= N_NODES) return;
    int w = node >> 1;
    int sh = 16 + 8 * (node & 1);  // dst byte lane
    int acc = off[node];
    for (int c = 0; c < NPART; ++c) {
        bases[(size_t)c * N_NODES + node] = acc;
        acc += (int)((p[(size_t)c * NWORD + w] >> sh) & 0xffu);
    }
}

// scatter via LDS re-histogram (dst only, u16-packed): the LDS atomicAdd
// return value IS the within-(chunk,dst) slot. No global atomics.
__global__ __launch_bounds__(256, 1) void k_scatter(const int* __restrict__ src,
                                                    const int* __restrict__ dst,
                                                    const int* __restrict__ bases,
                                                    int* __restrict__ csr) {
    __shared__ unsigned h[NWORD];  // 100,000 B
    int t = threadIdx.x;
    int base = blockIdx.x * CHUNK;
    const int* bp = bases + (size_t)blockIdx.x * N_NODES;
    for (int w = t; w < NWORD; w += 256) h[w] = 0u;
    __syncthreads();
    for (int j = t; j < CHUNK; j += 256) {
        int s = src[base + j], d = dst[base + j];
        if (s == d) continue;
        unsigned old = atomicAdd(&h[d >> 1], (d & 1) ? 65536u : 1u);
        unsigned pw = (d & 1) ? (old >> 16) : (old & 0xffffu);
        csr[bp[d] + (int)pw] = s;
    }
}

// ---------------- compute kernels ----------------

// x0: feature -> out col 0 (fp32) and XB = y0 = dinv * x (fp16, TWO half-tables).
// Also zeroes row N of both halves (the predication zero-row for hop gathers).
__global__ void k_x0(const float4* __restrict__ feat4, float4* __restrict__ out4,
                     uint2* __restrict__ y0, const float* __restrict__ dinv) {
    int t = blockIdx.x * blockDim.x + threadIdx.x;  // over (N+1)*16
    if (t >= (N_NODES + 1) * 16) return;
    int row = t >> 4, c = t & 15;
    uint2* slot = y0 + (size_t)(c >> 3) * HALF_U2 + (size_t)row * 8 + (c & 7);
    if (row < N_NODES) {
        float4 v = feat4[t];
        out4[(size_t)row * (OUT_STRIDE / 4) + c] = v;
        float di = dinv[row];
        uint2 w;
        w.x = pack_h2(v.x * di, v.y * di);
        w.y = pack_h2(v.z * di, v.w * di);
        *slot = w;
    } else {
        *slot = make_uint2(0u, 0u);  // zero row (both halves covered by c=0..15)
    }
}

// Half-feature hop pass: 8 nodes per wave, 8 lanes x 8B per node -> one gather
// instruction fetches 8 rows of 64B from the 3.2MB L2-RESIDENT half-table.
// Weight-free accumulate: t_i = sum y[j] + y[i]; out = dinv*t; y' = dinv^2*t.
// Two passes per hop (feature halves), fully independent, bit-identical math.
template <bool WRITE_HALF>
__global__ __launch_bounds__(256) void k_hop8(
    const uint2* __restrict__ yin,   // half-table base: (N+1) x 8 x uint2
    float4* __restrict__ outcol4,    // (float4*)out + k*16 + h*8; row stride 144
    uint2* __restrict__ yout,        // half-table base
    const int* __restrict__ off, const int* __restrict__ csr,
    const float* __restrict__ dinv) {
    int ow = (blockIdx.x * blockDim.x + threadIdx.x) >> 6;  // octet id
    if (ow >= NOCT) return;
    int lane = threadIdx.x & 63;
    int f = lane & 7;                  // feature quad within half: [4f, 4f+4)
    int node = ow * 8 + (lane >> 3);   // < 50000 exactly
    int e0 = off[node], e1 = off[node + 1];
    float di = dinv[node];
    uint2 sv = yin[(size_t)node * 8 + f];
    float2 lo = unpack_h2(sv.x), hi = unpack_h2(sv.y);
    float a0 = lo.x, a1 = lo.y, a2 = hi.x, a3 = hi.y;  // self term

    int nm = e1 - e0;  // wave-wide max degree over 8 nodes
    #pragma unroll
    for (int d = 32; d; d >>= 1) nm = max(nm, __shfl_xor(nm, d, 64));

    auto FETCH = [&](int j) -> int {
        int idx = e0 + j;
        int c = csr[idx < e1 ? idx : 0];  // safe broadcast addr
        return (idx < e1) ? c : N_NODES;  // zero row when exhausted
    };

    int c0 = FETCH(0), c1 = FETCH(1), c2 = FETCH(2), c3 = FETCH(3);
    for (int j = 0; j < nm; j += 4) {
        int d0 = FETCH(j + 4), d1 = FETCH(j + 5), d2 = FETCH(j + 6), d3 = FETCH(j + 7);
        uint2 q0 = yin[(size_t)c0 * 8 + f];
        uint2 q1 = yin[(size_t)c1 * 8 + f];
        uint2 q2 = yin[(size_t)c2 * 8 + f];
        uint2 q3 = yin[(size_t)c3 * 8 + f];
        float2 t;
        t = unpack_h2(q0.x); a0 += t.x; a1 += t.y;
        t = unpack_h2(q0.y); a2 += t.x; a3 += t.y;
        t = unpack_h2(q1.x); a0 += t.x; a1 += t.y;
        t = unpack_h2(q1.y); a2 += t.x; a3 += t.y;
        t = unpack_h2(q2.x); a0 += t.x; a1 += t.y;
        t = unpack_h2(q2.y); a2 += t.x; a3 += t.y;
        t = unpack_h2(q3.x); a0 += t.x; a1 += t.y;
        t = unpack_h2(q3.y); a2 += t.x; a3 += t.y;
        c0 = d0; c1 = d1; c2 = d2; c3 = d3;
    }

    outcol4[(size_t)node * (OUT_STRIDE / 4) + f] =
        make_float4(di * a0, di * a1, di * a2, di * a3);
    if (WRITE_HALF) {
        float di2 = di * di;
        uint2 w;
        w.x = pack_h2(di2 * a0, di2 * a1);
        w.y = pack_h2(di2 * a2, di2 * a3);
        yout[(size_t)node * 8 + f] = w;
        if (blockIdx.x == 0 && threadIdx.x < 8)
            yout[(size_t)N_NODES * 8 + threadIdx.x] = make_uint2(0u, 0u);  // zero row
    }
}

// ---------------- launch ----------------

extern "C" void kernel_launch(void* const* d_in, const int* in_sizes, int n_in,
                              void* d_out, int out_size, void* d_ws, size_t ws_size,
                              hipStream_t stream) {
    const float* feature = (const float*)d_in[0];
    const int* edge = (const int*)d_in[1];
    const int* src = edge;            // edge_index[0]
    const int* dst = edge + N_EDGES;  // edge_index[1]
    float* out = (float*)d_out;
    char* ws = (char*)d_ws;

    unsigned* p     = (unsigned*)(ws + OFF_P);
    int*      bases = (int*)(ws + OFF_BASES);
    int*      off   = (int*)(ws + OFF_OFF);
    int*      bsum  = (int*)(ws + OFF_BSUM);
    unsigned* totW  = (unsigned*)(ws + OFF_TOTW);
    float*    dinv  = (float*)(ws + OFF_DINV);
    int*      csr   = (int*)(ws + OFF_CSR);
    uint2*    xa    = (uint2*)(ws + OFF_XA);
    uint2*    xb    = (uint2*)(ws + OFF_XB);

    const int TB = 256;
    const int NB_NODES = (N_NODES + TB - 1) / TB;
    // ---- build normalization + CSR: zero global atomics, zero memsets
    k_hist<<<NPART, 256, 0, stream>>>(src, dst, p);
    k_sum<<<(NWORD + TB - 1) / TB, TB, 0, stream>>>(p, dinv, totW);
    k_x0<<<((N_NODES + 1) * 16 + TB - 1) / TB, TB, 0, stream>>>(
        (const float4*)feature, (float4*)out, xb, dinv);
    k_scan_sums<<<SCAN_NB, 256, 0, stream>>>(totW, bsum);
    k_scan_top<<<1, 64, 0, stream>>>(bsum);
    k_scan_downA<<<SCAN_NB, 256, 0, stream>>>(totW, bsum, off);
    k_bases<<<NB_NODES, TB, 0, stream>>>(p, off, bases);
    k_scatter<<<NPART, 256, 0, stream>>>(src, dst, bases, csr);
    // ---- K hops x 2 half-feature passes, fp16 ping-pong (XB -> XA -> XB ...)
    const int hop_blocks = (NOCT * 64 + TB - 1) / TB;  // 1563
    for (int k = 1; k <= K_HOPS; ++k) {
        uint2* yinb  = (k & 1) ? xb : xa;
        uint2* youtb = (k & 1) ? xa : xb;
        for (int h = 0; h < 2; ++h) {
            const uint2* yin = yinb + (size_t)h * HALF_U2;
            uint2* yout      = youtb + (size_t)h * HALF_U2;
            float4* outcol4 = (float4*)out + (size_t)k * 16 + h * 8;
            if (k < K_HOPS)
                k_hop8<true><<<hop_blocks, TB, 0, stream>>>(yin, outcol4, yout, off, csr, dinv);
            else
                k_hop8<false><<<hop_blocks, TB, 0, stream>>>(yin, outcol4, nullptr, off, csr, dinv);
        }
    }
}

// Round 10
// 318.788 us; speedup vs baseline: 1.2013x; 1.2013x over previous
//
#include <hip/hip_runtime.h>
#include <hip/hip_fp16.h>

#define N_NODES 50000
#define N_EDGES 800000
#define D_FEAT 64
#define K_HOPS 8
#define OUT_STRIDE ((K_HOPS + 1) * D_FEAT)  // 576
#define NPART 128                 // edge-chunk partitions (1 block/CU @ 100KB LDS)
#define CHUNK (N_EDGES / NPART)   // 6250
#define NWORD (N_NODES / 2)       // 2 nodes per u32 histogram word

#define SCAN_WORDS 512            // words per scan block = 1024 nodes
#define SCAN_NB ((NWORD + SCAN_WORDS - 1) / SCAN_WORDS)  // 49

#define NOCT (N_NODES / 8)        // 6250 octets (8 nodes per wave)

// ---------------- ws layout (bytes) ----------------
// No global atomics anywhere; every buffer fully overwritten -> no memset.
// P word layout per node-pair w (nodes 2w, 2w+1): byte0=src(2w), byte1=src(2w+1),
// byte2=dst(2w), byte3=dst(2w+1). Per-chunk per-node counts << 255.
// y buffers: SINGLE full table (r9's half-split REVERTED: L2-residency null;
// hop cost is per-VMEM-instruction address processing, not capacity misses).
#define ALIGN256(x) (((x) + 255) & ~(size_t)255)
static const size_t OFF_P     = 0;                                           // u32[128][25000]
static const size_t OFF_BASES = OFF_P + (size_t)NPART * NWORD * 4;           // int[128][N]
static const size_t OFF_OFF   = ALIGN256(OFF_BASES + (size_t)NPART * N_NODES * 4); // int[N+1]
static const size_t OFF_BSUM  = ALIGN256(OFF_OFF   + (size_t)(N_NODES + 1) * 4);   // int[64]
static const size_t OFF_TOTW  = ALIGN256(OFF_BSUM  + 64 * 4);                // u32[NWORD]
static const size_t OFF_DINV  = ALIGN256(OFF_TOTW  + (size_t)NWORD * 4);     // float[N]
static const size_t OFF_CSR   = ALIGN256(OFF_DINV  + (size_t)N_NODES * 4);   // int[E]
static const size_t OFF_XA    = ALIGN256(OFF_CSR   + (size_t)N_EDGES * 4);   // half[(N+1)*64]
static const size_t OFF_XB    = ALIGN256(OFF_XA + (size_t)(N_NODES + 1) * D_FEAT * 2);

__device__ __forceinline__ unsigned pack_h2(float a, float b) {
    union { __half2 h; unsigned u; } c;
    c.h = __floats2half2_rn(a, b);
    return c.u;
}
__device__ __forceinline__ float2 unpack_h2(unsigned u) {
    union { unsigned u; __half2 h; } c;
    c.u = u;
    return __half22float2(c.h);
}

// ---------------- preprocessing: zero-global-atomic counting sort ----------------
// (identical to r8 -- one-change discipline)

__global__ __launch_bounds__(256, 1) void k_hist(const int* __restrict__ src,
                                                 const int* __restrict__ dst,
                                                 unsigned* __restrict__ p) {
    __shared__ unsigned h[NWORD];  // 100,000 B
    int t = threadIdx.x;
    int base = blockIdx.x * CHUNK;
    for (int w = t; w < NWORD; w += 256) h[w] = 0u;
    __syncthreads();
    for (int j = t; j < CHUNK; j += 256) {
        int s = src[base + j], d = dst[base + j];
        if (s != d) {
            atomicAdd(&h[s >> 1], 1u << (8 * (s & 1)));        // src: bytes 0/1
            atomicAdd(&h[d >> 1], 65536u << (8 * (d & 1)));    // dst: bytes 2/3
        }
    }
    __syncthreads();
    unsigned* o = p + (size_t)blockIdx.x * NWORD;
    for (int w = t; w < NWORD; w += 256) o[w] = h[w];
}

__global__ void k_sum(const unsigned* __restrict__ p, float* __restrict__ dinv,
                      unsigned* __restrict__ totW) {
    int w = blockIdx.x * blockDim.x + threadIdx.x;
    if (w >= NWORD) return;
    unsigned s0 = 0, s1 = 0, s2 = 0, s3 = 0;
    #pragma unroll 4
    for (int c = 0; c < NPART; c += 4) {
        s0 += p[(size_t)(c + 0) * NWORD + w];
        s1 += p[(size_t)(c + 1) * NWORD + w];
        s2 += p[(size_t)(c + 2) * NWORD + w];
        s3 += p[(size_t)(c + 3) * NWORD + w];
    }
    unsigned s = (s0 + s1) + (s2 + s3);
    dinv[2 * w + 0] = rsqrtf((float)((s & 0xffu) + 1u));          // +1 self loop
    dinv[2 * w + 1] = rsqrtf((float)(((s >> 8) & 0xffu) + 1u));
    totW[w] = ((s >> 16) & 0xffu) | ((s >> 24) << 16);            // dst degs packed u16
}

__global__ void k_scan_sums(const unsigned* __restrict__ totW, int* __restrict__ bsum) {
    __shared__ int lds[256];
    int b = blockIdx.x, t = threadIdx.x;
    int wend = min((b + 1) * SCAN_WORDS, NWORD);
    int tot = 0;
    for (int w = b * SCAN_WORDS + t; w < wend; w += 256) {
        unsigned v = totW[w];
        tot += (int)(v & 0xffffu) + (int)(v >> 16);
    }
    lds[t] = tot; __syncthreads();
    for (int str = 128; str > 0; str >>= 1) {
        if (t < str) lds[t] += lds[t + str];
        __syncthreads();
    }
    if (t == 0) bsum[b] = lds[0];
}

__global__ void k_scan_top(int* __restrict__ bsum) {
    int lane = threadIdx.x;  // blockDim = 64
    int orig = (lane < SCAN_NB) ? bsum[lane] : 0;
    int v = orig;
    for (int d = 1; d < 64; d <<= 1) {
        int u = __shfl_up(v, d, 64);
        if (lane >= d) v += u;
    }
    if (lane < SCAN_NB) bsum[lane] = v - orig;  // exclusive
}

__global__ void k_scan_downA(const unsigned* __restrict__ totW, const int* __restrict__ bsum,
                             int* __restrict__ off) {
    __shared__ int lds[256];
    int b = blockIdx.x, t = threadIdx.x;
    int w0 = b * SCAN_WORDS + 2 * t;
    unsigned t0 = (w0 < NWORD) ? totW[w0] : 0u;
    unsigned t1 = (w0 + 1 < NWORD) ? totW[w0 + 1] : 0u;
    int n[4] = { (int)(t0 & 0xffffu), (int)(t0 >> 16),
                 (int)(t1 & 0xffffu), (int)(t1 >> 16) };
    int tsum = (n[0] + n[1]) + (n[2] + n[3]);
    lds[t] = tsum; __syncthreads();
    int x = tsum;
    for (int d = 1; d < 256; d <<= 1) {   // Hillis-Steele inclusive scan
        int u = (t >= d) ? lds[t - d] : 0;
        __syncthreads();
        x += u;
        lds[t] = x;
        __syncthreads();
    }
    int pfx = (x - tsum) + bsum[b];
    #pragma unroll
    for (int j = 0; j < 4; ++j) {
        int node = 2 * w0 + j;
        if (node < N_NODES) {
            off[node] = pfx;
            pfx += n[j];
        } else if (node == N_NODES) {
            off[node] = pfx;
        }
    }
}

__global__ void k_bases(const unsigned* __restrict__ p, const int* __restrict__ off,
                        int* __restrict__ bases) {
    int node = blockIdx.x * blockDim.x + threadIdx.x;
    if (node >= N_NODES) return;
    int w = node >> 1;
    int sh = 16 + 8 * (node & 1);  // dst byte lane
    int acc = off[node];
    for (int c = 0; c < NPART; ++c) {
        bases[(size_t)c * N_NODES + node] = acc;
        acc += (int)((p[(size_t)c * NWORD + w] >> sh) & 0xffu);
    }
}

__global__ __launch_bounds__(256, 1) void k_scatter(const int* __restrict__ src,
                                                    const int* __restrict__ dst,
                                                    const int* __restrict__ bases,
                                                    int* __restrict__ csr) {
    __shared__ unsigned h[NWORD];  // 100,000 B
    int t = threadIdx.x;
    int base = blockIdx.x * CHUNK;
    const int* bp = bases + (size_t)blockIdx.x * N_NODES;
    for (int w = t; w < NWORD; w += 256) h[w] = 0u;
    __syncthreads();
    for (int j = t; j < CHUNK; j += 256) {
        int s = src[base + j], d = dst[base + j];
        if (s == d) continue;
        unsigned old = atomicAdd(&h[d >> 1], (d & 1) ? 65536u : 1u);
        unsigned pw = (d & 1) ? (old >> 16) : (old & 0xffffu);
        csr[bp[d] + (int)pw] = s;
    }
}

// ---------------- compute kernels ----------------

// x0: feature -> out col 0 (fp32) and XB = y0 = dinv * x (fp16, single table).
// Also zeroes row N (the predication zero-row for hop gathers).
__global__ void k_x0(const float4* __restrict__ feat4, float4* __restrict__ out4,
                     uint2* __restrict__ y0, const float* __restrict__ dinv) {
    int t = blockIdx.x * blockDim.x + threadIdx.x;  // over (N+1)*16
    if (t >= (N_NODES + 1) * 16) return;
    int row = t >> 4;
    if (row < N_NODES) {
        float4 v = feat4[t];
        out4[(size_t)row * (OUT_STRIDE / 4) + (t & 15)] = v;
        float di = dinv[row];
        uint2 w;
        w.x = pack_h2(v.x * di, v.y * di);
        w.y = pack_h2(v.z * di, v.w * di);
        y0[t] = w;
    } else {
        y0[t] = make_uint2(0u, 0u);  // zero row
    }
}

// Octet hop: 8 nodes/wave, 8 lanes/node, 16B (uint4) per lane -> one gather
// instruction covers 8 edges (8 x 128B rows): HALF the gather instrs of r8.
// csr via vector load + shuffle broadcast: ONE coalesced VMEM per 64 edge
// slots (vs one broadcast VMEM per 4 edges). Per-edge VMEM instrs ~3.5x down;
// byte traffic unchanged (r9 null: capacity misses aren't the cost; the
// ~31cyc/VMEM address-divergence processing is the theory under test).
// Weight-free accumulate (fp32, same edge order -> bit-identical output).
template <bool WRITE_HALF>
__global__ __launch_bounds__(256) void k_hopv(
    const uint4* __restrict__ yin,   // (N+1) x 8 x uint4 (128B rows)
    float4* __restrict__ outcol4,    // (float4*)out + k*16; row stride 144
    uint4* __restrict__ yout,
    const int* __restrict__ off, const int* __restrict__ csr,
    const float* __restrict__ dinv) {
    int ow = (blockIdx.x * blockDim.x + threadIdx.x) >> 6;  // octet id
    if (ow >= NOCT) return;
    int lane = threadIdx.x & 63;
    int f = lane & 7;                  // 16B slot: features [8f, 8f+8)
    int node = ow * 8 + (lane >> 3);   // < 50000 exactly
    int e0 = off[node], e1 = off[node + 1];
    int deg = e1 - e0;
    float di = dinv[node];
    uint4 sv = yin[(size_t)node * 8 + f];
    float2 u;
    float a0, a1, a2, a3, a4, a5, a6, a7;
    u = unpack_h2(sv.x); a0 = u.x; a1 = u.y;
    u = unpack_h2(sv.y); a2 = u.x; a3 = u.y;
    u = unpack_h2(sv.z); a4 = u.x; a5 = u.y;
    u = unpack_h2(sv.w); a6 = u.x; a7 = u.y;

    int nm = deg;  // wave-wide max degree over the 8 nodes
    #pragma unroll
    for (int d = 32; d; d >>= 1) nm = max(nm, __shfl_xor(nm, d, 64));

    int gbase = lane & ~7;  // first lane of this node's 8-lane group

    // vector csr load: lane f holds entry e0+j+f (clamped safe; garbage
    // entries are valid node ids from csr and get masked after the shuffle)
    int cvec = csr[min(e0 + f, N_EDGES - 1)];
    for (int j = 0; j < nm; j += 8) {
        int cnext = csr[min(e0 + j + 8 + f, N_EDGES - 1)];
        int v0 = (j + 0 < deg) ? __shfl(cvec, gbase + 0, 64) : N_NODES;
        int v1 = (j + 1 < deg) ? __shfl(cvec, gbase + 1, 64) : N_NODES;
        int v2 = (j + 2 < deg) ? __shfl(cvec, gbase + 2, 64) : N_NODES;
        int v3 = (j + 3 < deg) ? __shfl(cvec, gbase + 3, 64) : N_NODES;
        int v4 = (j + 4 < deg) ? __shfl(cvec, gbase + 4, 64) : N_NODES;
        int v5 = (j + 5 < deg) ? __shfl(cvec, gbase + 5, 64) : N_NODES;
        int v6 = (j + 6 < deg) ? __shfl(cvec, gbase + 6, 64) : N_NODES;
        int v7 = (j + 7 < deg) ? __shfl(cvec, gbase + 7, 64) : N_NODES;
        uint4 q0 = yin[(size_t)v0 * 8 + f];
        uint4 q1 = yin[(size_t)v1 * 8 + f];
        uint4 q2 = yin[(size_t)v2 * 8 + f];
        uint4 q3 = yin[(size_t)v3 * 8 + f];
        uint4 q4 = yin[(size_t)v4 * 8 + f];
        uint4 q5 = yin[(size_t)v5 * 8 + f];
        uint4 q6 = yin[(size_t)v6 * 8 + f];
        uint4 q7 = yin[(size_t)v7 * 8 + f];
        u = unpack_h2(q0.x); a0 += u.x; a1 += u.y;
        u = unpack_h2(q0.y); a2 += u.x; a3 += u.y;
        u = unpack_h2(q0.z); a4 += u.x; a5 += u.y;
        u = unpack_h2(q0.w); a6 += u.x; a7 += u.y;
        u = unpack_h2(q1.x); a0 += u.x; a1 += u.y;
        u = unpack_h2(q1.y); a2 += u.x; a3 += u.y;
        u = unpack_h2(q1.z); a4 += u.x; a5 += u.y;
        u = unpack_h2(q1.w); a6 += u.x; a7 += u.y;
        u = unpack_h2(q2.x); a0 += u.x; a1 += u.y;
        u = unpack_h2(q2.y); a2 += u.x; a3 += u.y;
        u = unpack_h2(q2.z); a4 += u.x; a5 += u.y;
        u = unpack_h2(q2.w); a6 += u.x; a7 += u.y;
        u = unpack_h2(q3.x); a0 += u.x; a1 += u.y;
        u = unpack_h2(q3.y); a2 += u.x; a3 += u.y;
        u = unpack_h2(q3.z); a4 += u.x; a5 += u.y;
        u = unpack_h2(q3.w); a6 += u.x; a7 += u.y;
        u = unpack_h2(q4.x); a0 += u.x; a1 += u.y;
        u = unpack_h2(q4.y); a2 += u.x; a3 += u.y;
        u = unpack_h2(q4.z); a4 += u.x; a5 += u.y;
        u = unpack_h2(q4.w); a6 += u.x; a7 += u.y;
        u = unpack_h2(q5.x); a0 += u.x; a1 += u.y;
        u = unpack_h2(q5.y); a2 += u.x; a3 += u.y;
        u = unpack_h2(q5.z); a4 += u.x; a5 += u.y;
        u = unpack_h2(q5.w); a6 += u.x; a7 += u.y;
        u = unpack_h2(q6.x); a0 += u.x; a1 += u.y;
        u = unpack_h2(q6.y); a2 += u.x; a3 += u.y;
        u = unpack_h2(q6.z); a4 += u.x; a5 += u.y;
        u = unpack_h2(q6.w); a6 += u.x; a7 += u.y;
        u = unpack_h2(q7.x); a0 += u.x; a1 += u.y;
        u = unpack_h2(q7.y); a2 += u.x; a3 += u.y;
        u = unpack_h2(q7.z); a4 += u.x; a5 += u.y;
        u = unpack_h2(q7.w); a6 += u.x; a7 += u.y;
        cvec = cnext;
    }

    size_t orow = (size_t)node * (OUT_STRIDE / 4) + 2 * f;
    outcol4[orow]     = make_float4(di * a0, di * a1, di * a2, di * a3);
    outcol4[orow + 1] = make_float4(di * a4, di * a5, di * a6, di * a7);
    if (WRITE_HALF) {
        float di2 = di * di;
        uint4 w;
        w.x = pack_h2(di2 * a0, di2 * a1);
        w.y = pack_h2(di2 * a2, di2 * a3);
        w.z = pack_h2(di2 * a4, di2 * a5);
        w.w = pack_h2(di2 * a6, di2 * a7);
        yout[(size_t)node * 8 + f] = w;
        if (blockIdx.x == 0 && threadIdx.x < 8)
            yout[(size_t)N_NODES * 8 + threadIdx.x] = make_uint4(0u, 0u, 0u, 0u);
    }
}

// ---------------- launch ----------------

extern "C" void kernel_launch(void* const* d_in, const int* in_sizes, int n_in,
                              void* d_out, int out_size, void* d_ws, size_t ws_size,
                              hipStream_t stream) {
    const float* feature = (const float*)d_in[0];
    const int* edge = (const int*)d_in[1];
    const int* src = edge;            // edge_index[0]
    const int* dst = edge + N_EDGES;  // edge_index[1]
    float* out = (float*)d_out;
    char* ws = (char*)d_ws;

    unsigned* p     = (unsigned*)(ws + OFF_P);
    int*      bases = (int*)(ws + OFF_BASES);
    int*      off   = (int*)(ws + OFF_OFF);
    int*      bsum  = (int*)(ws + OFF_BSUM);
    unsigned* totW  = (unsigned*)(ws + OFF_TOTW);
    float*    dinv  = (float*)(ws + OFF_DINV);
    int*      csr   = (int*)(ws + OFF_CSR);
    uint4*    xa    = (uint4*)(ws + OFF_XA);
    uint4*    xb    = (uint4*)(ws + OFF_XB);

    const int TB = 256;
    const int NB_NODES = (N_NODES + TB - 1) / TB;
    // ---- build normalization + CSR: zero global atomics, zero memsets
    k_hist<<<NPART, 256, 0, stream>>>(src, dst, p);
    k_sum<<<(NWORD + TB - 1) / TB, TB, 0, stream>>>(p, dinv, totW);
    k_x0<<<((N_NODES + 1) * 16 + TB - 1) / TB, TB, 0, stream>>>(
        (const float4*)feature, (float4*)out, (uint2*)xb, dinv);
    k_scan_sums<<<SCAN_NB, 256, 0, stream>>>(totW, bsum);
    k_scan_top<<<1, 64, 0, stream>>>(bsum);
    k_scan_downA<<<SCAN_NB, 256, 0, stream>>>(totW, bsum, off);
    k_bases<<<NB_NODES, TB, 0, stream>>>(p, off, bases);
    k_scatter<<<NPART, 256, 0, stream>>>(src, dst, bases, csr);
    // ---- K hops, fp16 ping-pong y buffers (XB -> XA -> XB -> ...)
    const int hop_blocks = (NOCT * 64 + TB - 1) / TB;  // 1563
    for (int k = 1; k <= K_HOPS; ++k) {
        const uint4* yin = (k & 1) ? xb : xa;
        uint4* yout      = (k & 1) ? xa : xb;
        float4* outcol4 = (float4*)out + (size_t)k * 16;
        if (k < K_HOPS)
            k_hopv<true><<<hop_blocks, TB, 0, stream>>>(yin, outcol4, yout, off, csr, dinv);
        else
            k_hopv<false><<<hop_blocks, TB, 0, stream>>>(yin, outcol4, nullptr, off, csr, dinv);
    }
}

// Round 11
// 296.924 us; speedup vs baseline: 1.2898x; 1.0736x over previous
//
#include <hip/hip_runtime.h>
#include <hip/hip_fp16.h>
#include <hip/hip_fp8.h>

#define N_NODES 50000
#define N_EDGES 800000
#define D_FEAT 64
#define K_HOPS 8
#define OUT_STRIDE ((K_HOPS + 1) * D_FEAT)  // 576
#define NPART 128                 // edge-chunk partitions (1 block/CU @ 100KB LDS)
#define CHUNK (N_EDGES / NPART)   // 6250
#define NWORD (N_NODES / 2)       // 2 nodes per u32 histogram word

#define SCAN_WORDS 512            // words per scan block = 1024 nodes
#define SCAN_NB ((NWORD + SCAN_WORDS - 1) / SCAN_WORDS)  // 49

#define NOCT (N_NODES / 8)        // 6250 octets (8 nodes per wave)

// ---------------- ws layout (bytes) ----------------
// No global atomics anywhere; every buffer fully overwritten -> no memset.
// y tables are fp8 e4m3 (OCP): 64 features x 1B = 64B row = ONE 64B sector per
// edge gather. r8/r9/r10 triangulated the hop wall as a per-sector fee
// (~13.7ps/sector + ~10ps/edge, constant across structures); fp16's 128B rows
// are geometry-forced to 2 sectors/edge. fp32 accumulate, fp32 out columns.
#define ALIGN256(x) (((x) + 255) & ~(size_t)255)
static const size_t OFF_P     = 0;                                           // u32[128][25000]
static const size_t OFF_BASES = OFF_P + (size_t)NPART * NWORD * 4;           // int[128][N]
static const size_t OFF_OFF   = ALIGN256(OFF_BASES + (size_t)NPART * N_NODES * 4); // int[N+1]
static const size_t OFF_BSUM  = ALIGN256(OFF_OFF   + (size_t)(N_NODES + 1) * 4);   // int[64]
static const size_t OFF_TOTW  = ALIGN256(OFF_BSUM  + 64 * 4);                // u32[NWORD]
static const size_t OFF_DINV  = ALIGN256(OFF_TOTW  + (size_t)NWORD * 4);     // float[N]
static const size_t OFF_CSR   = ALIGN256(OFF_DINV  + (size_t)N_NODES * 4);   // int[E]
static const size_t OFF_XA    = ALIGN256(OFF_CSR   + (size_t)N_EDGES * 4);   // fp8[(N+1)*64]
static const size_t OFF_XB    = ALIGN256(OFF_XA + (size_t)(N_NODES + 1) * D_FEAT);

// ---- fp8 e4m3 helpers (hip_fp8.h OCP types; HW cvt on gfx950) ----
__device__ __forceinline__ float2 fp8x2_to_f2(unsigned short s) {
    __hip_fp8x2_e4m3 v;
    v.__x = (__hip_fp8x2_storage_t)s;
    return (float2)v;
}
__device__ __forceinline__ unsigned short f2_to_fp8x2(float a, float b) {
    __hip_fp8x2_e4m3 v(make_float2(a, b));
    return (unsigned short)v.__x;
}
__device__ __forceinline__ unsigned pack_fp8x4(float a, float b, float c, float d) {
    return (unsigned)f2_to_fp8x2(a, b) | ((unsigned)f2_to_fp8x2(c, d) << 16);
}

// ---------------- preprocessing: zero-global-atomic counting sort ----------------
// (identical to r8/r10 -- one-change discipline)

__global__ __launch_bounds__(256, 1) void k_hist(const int* __restrict__ src,
                                                 const int* __restrict__ dst,
                                                 unsigned* __restrict__ p) {
    __shared__ unsigned h[NWORD];  // 100,000 B
    int t = threadIdx.x;
    int base = blockIdx.x * CHUNK;
    for (int w = t; w < NWORD; w += 256) h[w] = 0u;
    __syncthreads();
    for (int j = t; j < CHUNK; j += 256) {
        int s = src[base + j], d = dst[base + j];
        if (s != d) {
            atomicAdd(&h[s >> 1], 1u << (8 * (s & 1)));        // src: bytes 0/1
            atomicAdd(&h[d >> 1], 65536u << (8 * (d & 1)));    // dst: bytes 2/3
        }
    }
    __syncthreads();
    unsigned* o = p + (size_t)blockIdx.x * NWORD;
    for (int w = t; w < NWORD; w += 256) o[w] = h[w];
}

__global__ void k_sum(const unsigned* __restrict__ p, float* __restrict__ dinv,
                      unsigned* __restrict__ totW) {
    int w = blockIdx.x * blockDim.x + threadIdx.x;
    if (w >= NWORD) return;
    unsigned s0 = 0, s1 = 0, s2 = 0, s3 = 0;
    #pragma unroll 4
    for (int c = 0; c < NPART; c += 4) {
        s0 += p[(size_t)(c + 0) * NWORD + w];
        s1 += p[(size_t)(c + 1) * NWORD + w];
        s2 += p[(size_t)(c + 2) * NWORD + w];
        s3 += p[(size_t)(c + 3) * NWORD + w];
    }
    unsigned s = (s0 + s1) + (s2 + s3);
    dinv[2 * w + 0] = rsqrtf((float)((s & 0xffu) + 1u));          // +1 self loop
    dinv[2 * w + 1] = rsqrtf((float)(((s >> 8) & 0xffu) + 1u));
    totW[w] = ((s >> 16) & 0xffu) | ((s >> 24) << 16);            // dst degs packed u16
}

__global__ void k_scan_sums(const unsigned* __restrict__ totW, int* __restrict__ bsum) {
    __shared__ int lds[256];
    int b = blockIdx.x, t = threadIdx.x;
    int wend = min((b + 1) * SCAN_WORDS, NWORD);
    int tot = 0;
    for (int w = b * SCAN_WORDS + t; w < wend; w += 256) {
        unsigned v = totW[w];
        tot += (int)(v & 0xffffu) + (int)(v >> 16);
    }
    lds[t] = tot; __syncthreads();
    for (int str = 128; str > 0; str >>= 1) {
        if (t < str) lds[t] += lds[t + str];
        __syncthreads();
    }
    if (t == 0) bsum[b] = lds[0];
}

__global__ void k_scan_top(int* __restrict__ bsum) {
    int lane = threadIdx.x;  // blockDim = 64
    int orig = (lane < SCAN_NB) ? bsum[lane] : 0;
    int v = orig;
    for (int d = 1; d < 64; d <<= 1) {
        int u = __shfl_up(v, d, 64);
        if (lane >= d) v += u;
    }
    if (lane < SCAN_NB) bsum[lane] = v - orig;  // exclusive
}

__global__ void k_scan_downA(const unsigned* __restrict__ totW, const int* __restrict__ bsum,
                             int* __restrict__ off) {
    __shared__ int lds[256];
    int b = blockIdx.x, t = threadIdx.x;
    int w0 = b * SCAN_WORDS + 2 * t;
    unsigned t0 = (w0 < NWORD) ? totW[w0] : 0u;
    unsigned t1 = (w0 + 1 < NWORD) ? totW[w0 + 1] : 0u;
    int n[4] = { (int)(t0 & 0xffffu), (int)(t0 >> 16),
                 (int)(t1 & 0xffffu), (int)(t1 >> 16) };
    int tsum = (n[0] + n[1]) + (n[2] + n[3]);
    lds[t] = tsum; __syncthreads();
    int x = tsum;
    for (int d = 1; d < 256; d <<= 1) {   // Hillis-Steele inclusive scan
        int u = (t >= d) ? lds[t - d] : 0;
        __syncthreads();
        x += u;
        lds[t] = x;
        __syncthreads();
    }
    int pfx = (x - tsum) + bsum[b];
    #pragma unroll
    for (int j = 0; j < 4; ++j) {
        int node = 2 * w0 + j;
        if (node < N_NODES) {
            off[node] = pfx;
            pfx += n[j];
        } else if (node == N_NODES) {
            off[node] = pfx;
        }
    }
}

__global__ void k_bases(const unsigned* __restrict__ p, const int* __restrict__ off,
                        int* __restrict__ bases) {
    int node = blockIdx.x * blockDim.x + threadIdx.x;
    if (node >= N_NODES) return;
    int w = node >> 1;
    int sh = 16 + 8 * (node & 1);  // dst byte lane
    int acc = off[node];
    for (int c = 0; c < NPART; ++c) {
        bases[(size_t)c * N_NODES + node] = acc;
        acc += (int)((p[(size_t)c * NWORD + w] >> sh) & 0xffu);
    }
}

__global__ __launch_bounds__(256, 1) void k_scatter(const int* __restrict__ src,
                                                    const int* __restrict__ dst,
                                                    const int* __restrict__ bases,
                                                    int* __restrict__ csr) {
    __shared__ unsigned h[NWORD];  // 100,000 B
    int t = threadIdx.x;
    int base = blockIdx.x * CHUNK;
    const int* bp = bases + (size_t)blockIdx.x * N_NODES;
    for (int w = t; w < NWORD; w += 256) h[w] = 0u;
    __syncthreads();
    for (int j = t; j < CHUNK; j += 256) {
        int s = src[base + j], d = dst[base + j];
        if (s == d) continue;
        unsigned old = atomicAdd(&h[d >> 1], (d & 1) ? 65536u : 1u);
        unsigned pw = (d & 1) ? (old >> 16) : (old & 0xffffu);
        csr[bp[d] + (int)pw] = s;
    }
}

// ---------------- compute kernels ----------------

// x0: feature -> out col 0 (fp32) and XB = y0 = dinv * x (fp8 e4m3, 64B rows).
// Also zeroes row N (the predication zero-row for hop gathers; fp8 0 = 0x00).
__global__ void k_x0(const float4* __restrict__ feat4, float4* __restrict__ out4,
                     unsigned* __restrict__ y8, const float* __restrict__ dinv) {
    int t = blockIdx.x * blockDim.x + threadIdx.x;  // over (N+1)*16
    if (t >= (N_NODES + 1) * 16) return;
    int row = t >> 4;
    if (row < N_NODES) {
        float4 v = feat4[t];
        out4[(size_t)row * (OUT_STRIDE / 4) + (t & 15)] = v;
        float di = dinv[row];
        y8[t] = pack_fp8x4(v.x * di, v.y * di, v.z * di, v.w * di);
    } else {
        y8[t] = 0u;  // zero row
    }
}

// Octet hop, fp8 rows: 8 nodes/wave, 8 lanes/node, 8B (uint2 = 8 fp8) per
// lane -> 64B row -> ONE sector per edge (the r10 wall was 2 sectors/edge).
// csr via vector load + shuffle broadcast (proven in r10). fp32 accumulate;
// out col fp32; y' re-quantized to fp8 (absmax expected ~0.02-0.06).
template <bool WRITE_HALF>
__global__ __launch_bounds__(256) void k_hopf8(
    const uint2* __restrict__ yin,   // (N+1) x 8 x uint2 (64B rows)
    float4* __restrict__ outcol4,    // (float4*)out + k*16; row stride 144
    uint2* __restrict__ yout,
    const int* __restrict__ off, const int* __restrict__ csr,
    const float* __restrict__ dinv) {
    int ow = (blockIdx.x * blockDim.x + threadIdx.x) >> 6;  // octet id
    if (ow >= NOCT) return;
    int lane = threadIdx.x & 63;
    int f = lane & 7;                  // 8B slot: features [8f, 8f+8)
    int node = ow * 8 + (lane >> 3);   // < 50000 exactly
    int e0 = off[node], e1 = off[node + 1];
    int deg = e1 - e0;
    float di = dinv[node];
    float a0 = 0.f, a1 = 0.f, a2 = 0.f, a3 = 0.f;
    float a4 = 0.f, a5 = 0.f, a6 = 0.f, a7 = 0.f;
    {
        uint2 sv = yin[(size_t)node * 8 + f];  // self term
        float2 u;
        u = fp8x2_to_f2((unsigned short)(sv.x & 0xffffu)); a0 = u.x; a1 = u.y;
        u = fp8x2_to_f2((unsigned short)(sv.x >> 16));     a2 = u.x; a3 = u.y;
        u = fp8x2_to_f2((unsigned short)(sv.y & 0xffffu)); a4 = u.x; a5 = u.y;
        u = fp8x2_to_f2((unsigned short)(sv.y >> 16));     a6 = u.x; a7 = u.y;
    }

    int nm = deg;  // wave-wide max degree over the 8 nodes
    #pragma unroll
    for (int d = 32; d; d >>= 1) nm = max(nm, __shfl_xor(nm, d, 64));

    int gbase = lane & ~7;  // first lane of this node's 8-lane group

    #define ACC8(q)                                                        \
        {                                                                  \
            float2 u_;                                                     \
            u_ = fp8x2_to_f2((unsigned short)((q).x & 0xffffu));           \
            a0 += u_.x; a1 += u_.y;                                        \
            u_ = fp8x2_to_f2((unsigned short)((q).x >> 16));               \
            a2 += u_.x; a3 += u_.y;                                        \
            u_ = fp8x2_to_f2((unsigned short)((q).y & 0xffffu));           \
            a4 += u_.x; a5 += u_.y;                                        \
            u_ = fp8x2_to_f2((unsigned short)((q).y >> 16));               \
            a6 += u_.x; a7 += u_.y;                                        \
        }

    // vector csr load: lane f holds entry e0+j+f (clamped safe; garbage
    // entries beyond e1 never dereferenced -- masked to zero row).
    int cvec = csr[min(e0 + f, N_EDGES - 1)];
    for (int j = 0; j < nm; j += 8) {
        int cnext = csr[min(e0 + j + 8 + f, N_EDGES - 1)];
        int v0 = (j + 0 < deg) ? __shfl(cvec, gbase + 0, 64) : N_NODES;
        int v1 = (j + 1 < deg) ? __shfl(cvec, gbase + 1, 64) : N_NODES;
        int v2 = (j + 2 < deg) ? __shfl(cvec, gbase + 2, 64) : N_NODES;
        int v3 = (j + 3 < deg) ? __shfl(cvec, gbase + 3, 64) : N_NODES;
        int v4 = (j + 4 < deg) ? __shfl(cvec, gbase + 4, 64) : N_NODES;
        int v5 = (j + 5 < deg) ? __shfl(cvec, gbase + 5, 64) : N_NODES;
        int v6 = (j + 6 < deg) ? __shfl(cvec, gbase + 6, 64) : N_NODES;
        int v7 = (j + 7 < deg) ? __shfl(cvec, gbase + 7, 64) : N_NODES;
        uint2 q0 = yin[(size_t)v0 * 8 + f];
        uint2 q1 = yin[(size_t)v1 * 8 + f];
        uint2 q2 = yin[(size_t)v2 * 8 + f];
        uint2 q3 = yin[(size_t)v3 * 8 + f];
        uint2 q4 = yin[(size_t)v4 * 8 + f];
        uint2 q5 = yin[(size_t)v5 * 8 + f];
        uint2 q6 = yin[(size_t)v6 * 8 + f];
        uint2 q7 = yin[(size_t)v7 * 8 + f];
        ACC8(q0) ACC8(q1) ACC8(q2) ACC8(q3)
        ACC8(q4) ACC8(q5) ACC8(q6) ACC8(q7)
        cvec = cnext;
    }
    #undef ACC8

    size_t orow = (size_t)node * (OUT_STRIDE / 4) + 2 * f;
    outcol4[orow]     = make_float4(di * a0, di * a1, di * a2, di * a3);
    outcol4[orow + 1] = make_float4(di * a4, di * a5, di * a6, di * a7);
    if (WRITE_HALF) {
        float di2 = di * di;
        uint2 w;
        w.x = pack_fp8x4(di2 * a0, di2 * a1, di2 * a2, di2 * a3);
        w.y = pack_fp8x4(di2 * a4, di2 * a5, di2 * a6, di2 * a7);
        yout[(size_t)node * 8 + f] = w;
        if (blockIdx.x == 0 && threadIdx.x < 8)
            yout[(size_t)N_NODES * 8 + threadIdx.x] = make_uint2(0u, 0u);  // zero row
    }
}

// ---------------- launch ----------------

extern "C" void kernel_launch(void* const* d_in, const int* in_sizes, int n_in,
                              void* d_out, int out_size, void* d_ws, size_t ws_size,
                              hipStream_t stream) {
    const float* feature = (const float*)d_in[0];
    const int* edge = (const int*)d_in[1];
    const int* src = edge;            // edge_index[0]
    const int* dst = edge + N_EDGES;  // edge_index[1]
    float* out = (float*)d_out;
    char* ws = (char*)d_ws;

    unsigned* p     = (unsigned*)(ws + OFF_P);
    int*      bases = (int*)(ws + OFF_BASES);
    int*      off   = (int*)(ws + OFF_OFF);
    int*      bsum  = (int*)(ws + OFF_BSUM);
    unsigned* totW  = (unsigned*)(ws + OFF_TOTW);
    float*    dinv  = (float*)(ws + OFF_DINV);
    int*      csr   = (int*)(ws + OFF_CSR);
    uint2*    xa    = (uint2*)(ws + OFF_XA);
    uint2*    xb    = (uint2*)(ws + OFF_XB);

    const int TB = 256;
    const int NB_NODES = (N_NODES + TB - 1) / TB;
    // ---- build normalization + CSR: zero global atomics, zero memsets
    k_hist<<<NPART, 256, 0, stream>>>(src, dst, p);
    k_sum<<<(NWORD + TB - 1) / TB, TB, 0, stream>>>(p, dinv, totW);
    k_x0<<<((N_NODES + 1) * 16 + TB - 1) / TB, TB, 0, stream>>>(
        (const float4*)feature, (float4*)out, (unsigned*)xb, dinv);
    k_scan_sums<<<SCAN_NB, 256, 0, stream>>>(totW, bsum);
    k_scan_top<<<1, 64, 0, stream>>>(bsum);
    k_scan_downA<<<SCAN_NB, 256, 0, stream>>>(totW, bsum, off);
    k_bases<<<NB_NODES, TB, 0, stream>>>(p, off, bases);
    k_scatter<<<NPART, 256, 0, stream>>>(src, dst, bases, csr);
    // ---- K hops, fp8 ping-pong y buffers (XB -> XA -> XB -> ...)
    const int hop_blocks = (NOCT * 64 + TB - 1) / TB;  // 1563
    for (int k = 1; k <= K_HOPS; ++k) {
        const uint2* yin = (k & 1) ? xb : xa;
        uint2* yout      = (k & 1) ? xa : xb;
        float4* outcol4 = (float4*)out + (size_t)k * 16;
        if (k < K_HOPS)
            k_hopf8<true><<<hop_blocks, TB, 0, stream>>>(yin, outcol4, yout, off, csr, dinv);
        else
            k_hopf8<false><<<hop_blocks, TB, 0, stream>>>(yin, outcol4, nullptr, off, csr, dinv);
    }
}